// Round 9
// baseline (249.419 us; speedup 1.0000x reference)
//
#include <hip/hip_runtime.h>

#define NN 131072
#define DD 64
#define KK 1024

typedef __attribute__((ext_vector_type(8))) short short8v;
typedef __attribute__((ext_vector_type(4))) float float4v;
typedef __attribute__((ext_vector_type(4))) int int4v;

#define MFMA(a, b, c) __builtin_amdgcn_mfma_f32_16x16x32_bf16(a, b, c, 0, 0, 0)

__device__ __forceinline__ unsigned int umin32(unsigned int a, unsigned int b) { return a < b ? a : b; }
__device__ __forceinline__ unsigned int umax32(unsigned int a, unsigned int b) { return a > b ? a : b; }

// order-preserving float->uint, top 22 bits kept, 10-bit index in low bits.
__device__ __forceinline__ unsigned int packu(float u, int kk) {
    int b = __builtin_bit_cast(int, u);
    unsigned int key = (unsigned int)(b ^ ((b >> 31) | 0x80000000));
    return (key & 0xFFFFFC00u) | (unsigned int)kk;
}

// sorted-insert p into ascending triple (5 min/max)
#define PINS3(t0, t1, t2, p)                                   \
    { unsigned int _x0 = umax32(t0, p); t0 = umin32(t0, p);    \
      unsigned int _x1 = umax32(t1, _x0); t1 = umin32(t1, _x0);\
      t2 = umin32(t2, _x1); }

// numpy pairwise sum of squares, n=64 (bit-exact vs np.sum(x**2, axis=1))
__device__ __forceinline__ float np_sumsq64(const float* v) {
    float r[8];
#pragma unroll
    for (int j = 0; j < 8; ++j) r[j] = __fmul_rn(v[j], v[j]);
#pragma unroll
    for (int i = 8; i < 64; i += 8) {
#pragma unroll
        for (int j = 0; j < 8; ++j)
            r[j] = __fadd_rn(r[j], __fmul_rn(v[i + j], v[i + j]));
    }
    return __fadd_rn(__fadd_rn(__fadd_rn(r[0], r[1]), __fadd_rn(r[2], r[3])),
                     __fadd_rn(__fadd_rn(r[4], r[5]), __fadd_rn(r[6], r[7])));
}

// RNE bf16 hi/lo split: v = hi + lo + O(2^-18 |v|)
__device__ __forceinline__ void bf16split(float v, unsigned short& hb, unsigned short& lb) {
    unsigned int u = __builtin_bit_cast(unsigned int, v);
    unsigned int h = (u + 0x7FFFu + ((u >> 16) & 1u)) >> 16;
    float hf = __builtin_bit_cast(float, h << 16);
    float lo = __fsub_rn(v, hf);
    unsigned int ul = __builtin_bit_cast(unsigned int, lo);
    unsigned int lo16 = (ul + 0x7FFFu + ((ul >> 16) & 1u)) >> 16;
    hb = (unsigned short)h;
    lb = (unsigned short)lo16;
}

// ---------------- prep: split of (-2*cb) + packed bf16(se) ----------------
__global__ void vq_prep(const float* __restrict__ cb, unsigned short* __restrict__ cbh,
                        unsigned short* __restrict__ cbl, unsigned int* __restrict__ sehl) {
    int k = blockIdx.x * 64 + threadIdx.x;
    if (k >= KK) return;
    float v[DD];
    const float4* p = (const float4*)(cb + (size_t)k * DD);
#pragma unroll
    for (int i = 0; i < 16; ++i) {
        float4 q = p[i];
        v[4 * i + 0] = q.x; v[4 * i + 1] = q.y; v[4 * i + 2] = q.z; v[4 * i + 3] = q.w;
    }
    float se = np_sumsq64(v);
    unsigned short sh, sl;
    bf16split(se, sh, sl);
    sehl[k] = (unsigned int)sh | ((unsigned int)sl << 16);
    short8v* oh = (short8v*)(cbh + (size_t)k * DD);
    short8v* ol = (short8v*)(cbl + (size_t)k * DD);
#pragma unroll
    for (int q = 0; q < 8; ++q) {
        short8v hq, lq;
#pragma unroll
        for (int e = 0; e < 8; ++e) {
            unsigned short hb, lb;
            bf16split(-2.0f * v[q * 8 + e], hb, lb);   // pre-scaled by -2 (exact)
            hq[e] = (short)hb; lq[e] = (short)lb;
        }
        oh[q] = hq; ol[q] = lq;
    }
}

// ---------------- main: MFMA screen + exact rescore + quantize/loss ----------------
union SMem {
    struct { unsigned short xh[128 * 64]; unsigned short xl[128 * 64]; } x;  // 32 KB
    struct { unsigned short bh[2][64 * 64]; unsigned short bl[2][64 * 64]; } b;  // 32 KB
};

__global__ __launch_bounds__(256, 4)
void vq_main(const float* __restrict__ x, const float* __restrict__ cb,
             const unsigned short* __restrict__ cbh, const unsigned short* __restrict__ cbl,
             const unsigned int* __restrict__ sehl, float* __restrict__ out,
             double* __restrict__ acc, unsigned int* __restrict__ cnt) {
    __shared__ SMem sm;
    __shared__ unsigned int sehls[KK];   // 4 KB
    __shared__ float wls[4];

    float* qout = out + 1;
    float* idxf = out + 1 + (size_t)NN * DD;

    const int tid = threadIdx.x;
    const int rowBase = blockIdx.x * 128;
    const int l = tid & 63;
    const int w = tid >> 6;
    const int col = l & 15;
    const int g = l >> 4;

    int4v rbh[2], rbl[2];
    const int be_ = tid >> 2;            // entry 0..63
    const int bq_ = (tid & 3) * 2;       // first of 2 quads
#define LOAD_TILE(tt)                                                              \
    { const unsigned short* ph = cbh + ((size_t)((tt) * 64 + be_) * 64) + (tid & 3) * 16; \
      const unsigned short* pl = cbl + ((size_t)((tt) * 64 + be_) * 64) + (tid & 3) * 16; \
      rbh[0] = *(const int4v*)(ph); rbh[1] = *(const int4v*)(ph + 8);              \
      rbl[0] = *(const int4v*)(pl); rbl[1] = *(const int4v*)(pl + 8); }
#define WRITE_TILE(bufi)                                                           \
    { int4v* dh = (int4v*)sm.b.bh[bufi]; int4v* dl = (int4v*)sm.b.bl[bufi];        \
      dh[be_ * 8 + (bq_ ^ (be_ & 7))] = rbh[0];                                    \
      dh[be_ * 8 + ((bq_ + 1) ^ (be_ & 7))] = rbh[1];                              \
      dl[be_ * 8 + (bq_ ^ (be_ & 7))] = rbl[0];                                    \
      dl[be_ * 8 + ((bq_ + 1) ^ (be_ & 7))] = rbl[1]; }

    // ---- stage packed se -> LDS
    ((int4v*)sehls)[tid] = ((const int4v*)sehl)[tid];

    // ---- convert x tile to bf16 hi/lo, swizzled LDS store
    {
        int row = tid >> 1, db = (tid & 1) * 32;
        const float* xr = x + (size_t)(rowBase + row) * 64 + db;
#pragma unroll
        for (int jj = 0; jj < 4; ++jj) {
            float4 v0 = ((const float4*)xr)[2 * jj];
            float4 v1 = ((const float4*)xr)[2 * jj + 1];
            float vv[8] = {v0.x, v0.y, v0.z, v0.w, v1.x, v1.y, v1.z, v1.w};
            short8v hq, lq;
#pragma unroll
            for (int e = 0; e < 8; ++e) {
                unsigned short hb, lb;
                bf16split(vv[e], hb, lb);
                hq[e] = (short)hb; lq[e] = (short)lb;
            }
            int q = (tid & 1) * 4 + jj;
            int slot = row * 8 + (q ^ (row & 7));
            ((short8v*)sm.x.xh)[slot] = hq;
            ((short8v*)sm.x.xl)[slot] = lq;
        }
    }
    LOAD_TILE(0);
    __syncthreads();

    // ---- A fragments: rows w*32+col (set0), +16 (set1)
    short8v ah0s0, ah1s0, al0s0, al1s0, ah0s1, ah1s1, al0s1, al1s1;
    {
        int r0 = w * 32 + col;
        int r1 = r0 + 16;
        ah0s0 = ((short8v*)sm.x.xh)[r0 * 8 + ((0 + g) ^ (r0 & 7))];
        ah1s0 = ((short8v*)sm.x.xh)[r0 * 8 + ((4 + g) ^ (r0 & 7))];
        al0s0 = ((short8v*)sm.x.xl)[r0 * 8 + ((0 + g) ^ (r0 & 7))];
        al1s0 = ((short8v*)sm.x.xl)[r0 * 8 + ((4 + g) ^ (r0 & 7))];
        ah0s1 = ((short8v*)sm.x.xh)[r1 * 8 + ((0 + g) ^ (r1 & 7))];
        ah1s1 = ((short8v*)sm.x.xh)[r1 * 8 + ((4 + g) ^ (r1 & 7))];
        al0s1 = ((short8v*)sm.x.xl)[r1 * 8 + ((0 + g) ^ (r1 & 7))];
        al1s1 = ((short8v*)sm.x.xl)[r1 * 8 + ((4 + g) ^ (r1 & 7))];
    }
    __syncthreads();   // A-frags consumed; x region free for B tiles

    WRITE_TILE(0);
    LOAD_TILE(1);
    __syncthreads();

    // ones-A fragment: A[k]=1.0bf16 for k=0,1 (lanes g==0, j=0,1)
    const short8v onesA = __builtin_bit_cast(short8v,
        (int4v){(g == 0) ? (int)0x3F803F80 : 0, 0, 0, 0});
    const float4v zero4 = {0.f, 0.f, 0.f, 0.f};

    // ---- packed top-3 screen state
    unsigned int k0[8], k1[8], k2[8];
#pragma unroll
    for (int s = 0; s < 8; ++s) { k0[s] = 0xFFFFFFFFu; k1[s] = 0xFFFFFFFFu; k2[s] = 0xFFFFFFFFu; }

    for (int t = 0; t < 16; ++t) {
        if (t < 15) {
            WRITE_TILE((t + 1) & 1);
            if (t < 14) LOAD_TILE(t + 2);
        }
        const unsigned short* bhB = sm.b.bh[t & 1];
        const unsigned short* blB = sm.b.bl[t & 1];
#pragma unroll
        for (int c = 0; c < 4; ++c) {
            int ec = c * 16 + col;
            int be = ec * 8, sw = ec & 7;
            short8v bh0 = ((const short8v*)bhB)[be + ((0 + g) ^ sw)];
            short8v bh1 = ((const short8v*)bhB)[be + ((4 + g) ^ sw)];
            short8v bl0 = ((const short8v*)blB)[be + ((0 + g) ^ sw)];
            short8v bl1 = ((const short8v*)blB)[be + ((4 + g) ^ sw)];
            // se fragment: B[k=0]=se_hi, B[k=1]=se_lo for this column
            unsigned int sv = sehls[t * 64 + ec];
            short8v sf = __builtin_bit_cast(short8v,
                (int4v){(g == 0) ? (int)sv : 0, 0, 0, 0});
            float4v seAcc = MFMA(onesA, sf, zero4);
            float4v acc0 = seAcc, acc1 = seAcc;
            acc0 = MFMA(ah0s0, bh0, acc0);
            acc0 = MFMA(ah1s0, bh1, acc0);
            acc0 = MFMA(al0s0, bh0, acc0);
            acc0 = MFMA(al1s0, bh1, acc0);
            acc0 = MFMA(ah0s0, bl0, acc0);
            acc0 = MFMA(ah1s0, bl1, acc0);
            acc1 = MFMA(ah0s1, bh0, acc1);
            acc1 = MFMA(ah1s1, bh1, acc1);
            acc1 = MFMA(al0s1, bh0, acc1);
            acc1 = MFMA(al1s1, bh1, acc1);
            acc1 = MFMA(ah0s1, bl0, acc1);
            acc1 = MFMA(ah1s1, bl1, acc1);
            int kk = t * 64 + ec;
#pragma unroll
            for (int r = 0; r < 4; ++r) {
                unsigned int p0 = packu(acc0[r], kk);      // u = se - 2*dot
                PINS3(k0[r], k1[r], k2[r], p0);
                unsigned int p1 = packu(acc1[r], kk);
                PINS3(k0[4 + r], k1[4 + r], k2[4 + r], p1);
            }
        }
        __syncthreads();
    }

    // ---- merge top-3 across the 16 lanes of each group
#pragma unroll
    for (int s = 0; s < 8; ++s) {
#pragma unroll
        for (int m = 1; m < 16; m <<= 1) {
            unsigned int o0 = __shfl_xor(k0[s], m);
            unsigned int o1 = __shfl_xor(k1[s], m);
            unsigned int o2 = __shfl_xor(k2[s], m);
            PINS3(k0[s], k1[s], k2[s], o0);
            { unsigned int x1 = umax32(k1[s], o1); k1[s] = umin32(k1[s], o1);
              k2[s] = umin32(k2[s], x1); }
            k2[s] = umin32(k2[s], o2);
        }
    }

    // ---- exact rescore + aligned quantize/st/loss (2 passes: row sets 0,1)
    float lossLocal = 0.f;
    const int rr = (l & 15) >> 2;  // row-in-group
    const int j = l & 3;           // candidate slot (3 => duplicate 0)
    const int jj = (j == 3) ? 0 : j;
#pragma unroll
    for (int s = 0; s < 2; ++s) {
        unsigned int ckk = k0[s * 4];
#pragma unroll
        for (int r_ = 0; r_ < 4; ++r_) {
            if (rr == r_) {
                if (jj == 0) ckk = k0[s * 4 + r_];
                else if (jj == 1) ckk = k1[s * 4 + r_];
                else ckk = k2[s * 4 + r_];
            }
        }
        int ck = (int)(ckk & 1023u);
        int rowg = rowBase + w * 32 + s * 16 + g * 4 + rr;
        const float4* xr = (const float4*)(x + (size_t)rowg * 64);
        const float4* er = (const float4*)(cb + (size_t)ck * 64);
        // exact dot (sequential fma) + numpy-pairwise ||x||^2 and ||e||^2
        float dot = 0.f;
        float rs0 = 0.f, rs1 = 0.f, rs2 = 0.f, rs3 = 0.f, rs4 = 0.f, rs5 = 0.f, rs6 = 0.f, rs7 = 0.f;
        float es0 = 0.f, es1 = 0.f, es2 = 0.f, es3 = 0.f, es4 = 0.f, es5 = 0.f, es6 = 0.f, es7 = 0.f;
#pragma unroll
        for (int i = 0; i < 16; ++i) {
            float4 a4 = xr[i], e4 = er[i];
            dot = fmaf(a4.x, e4.x, dot);
            dot = fmaf(a4.y, e4.y, dot);
            dot = fmaf(a4.z, e4.z, dot);
            dot = fmaf(a4.w, e4.w, dot);
            if ((i & 1) == 0) {
                rs0 = __fadd_rn(rs0, __fmul_rn(a4.x, a4.x));
                rs1 = __fadd_rn(rs1, __fmul_rn(a4.y, a4.y));
                rs2 = __fadd_rn(rs2, __fmul_rn(a4.z, a4.z));
                rs3 = __fadd_rn(rs3, __fmul_rn(a4.w, a4.w));
                es0 = __fadd_rn(es0, __fmul_rn(e4.x, e4.x));
                es1 = __fadd_rn(es1, __fmul_rn(e4.y, e4.y));
                es2 = __fadd_rn(es2, __fmul_rn(e4.z, e4.z));
                es3 = __fadd_rn(es3, __fmul_rn(e4.w, e4.w));
            } else {
                rs4 = __fadd_rn(rs4, __fmul_rn(a4.x, a4.x));
                rs5 = __fadd_rn(rs5, __fmul_rn(a4.y, a4.y));
                rs6 = __fadd_rn(rs6, __fmul_rn(a4.z, a4.z));
                rs7 = __fadd_rn(rs7, __fmul_rn(a4.w, a4.w));
                es4 = __fadd_rn(es4, __fmul_rn(e4.x, e4.x));
                es5 = __fadd_rn(es5, __fmul_rn(e4.y, e4.y));
                es6 = __fadd_rn(es6, __fmul_rn(e4.z, e4.z));
                es7 = __fadd_rn(es7, __fmul_rn(e4.w, e4.w));
            }
        }
        float sa = __fadd_rn(__fadd_rn(__fadd_rn(rs0, rs1), __fadd_rn(rs2, rs3)),
                             __fadd_rn(__fadd_rn(rs4, rs5), __fadd_rn(rs6, rs7)));
        float seE = __fadd_rn(__fadd_rn(__fadd_rn(es0, es1), __fadd_rn(es2, es3)),
                              __fadd_rn(__fadd_rn(es4, es5), __fadd_rn(es6, es7)));
        float qd = __fsub_rn(__fadd_rn(sa, seE), __fmul_rn(2.f, dot));
#pragma unroll
        for (int m = 1; m < 4; m <<= 1) {
            float oq = __shfl_xor(qd, m);
            int ok = __shfl_xor(ck, m);
            if (oq < qd || (oq == qd && ok < ck)) { qd = oq; ck = ok; }
        }
        if (j == 0) idxf[rowg] = (float)ck;

        // ---- aligned store: 15 aligned float4 (e=3..62) + 4 scalars (e=0,1,2,63)
        const float* xrow = x + (size_t)rowg * 64;
        const float* qrow = cb + (size_t)ck * 64;
        float* ob = qout + (size_t)rowg * 64;   // out dword index 1+rowg*64
#pragma unroll
        for (int mi = 0; mi < 4; ++mi) {
            int m = j + mi * 4;
            if (m < 15) {
                float4 xv = *(const float4*)(xrow + 3 + 4 * m);   // hot, unaligned ok
                float4 qv = *(const float4*)(qrow + 3 + 4 * m);
                float dx = __fsub_rn(qv.x, xv.x);
                float dy = __fsub_rn(qv.y, xv.y);
                float dz = __fsub_rn(qv.z, xv.z);
                float dw = __fsub_rn(qv.w, xv.w);
                float4 o;
                o.x = __fadd_rn(xv.x, dx);
                o.y = __fadd_rn(xv.y, dy);
                o.z = __fadd_rn(xv.z, dz);
                o.w = __fadd_rn(xv.w, dw);
                *(float4*)(ob + 3 + 4 * m) = o;                    // 16B-aligned
                lossLocal = fmaf(dx, dx, lossLocal);
                lossLocal = fmaf(dy, dy, lossLocal);
                lossLocal = fmaf(dz, dz, lossLocal);
                lossLocal = fmaf(dw, dw, lossLocal);
            }
        }
        if (j == 3) {
#pragma unroll
            for (int e3 = 0; e3 < 4; ++e3) {
                int e = (e3 < 3) ? e3 : 63;
                float xv = xrow[e];
                float qv = qrow[e];
                float d = __fsub_rn(qv, xv);
                ob[e] = __fadd_rn(xv, d);
                lossLocal = fmaf(d, d, lossLocal);
            }
        }
    }

    // ---- block loss reduction -> device atomic; last block finalizes out[0]
#pragma unroll
    for (int m = 1; m < 64; m <<= 1) lossLocal += __shfl_xor(lossLocal, m);
    if (l == 0) wls[w] = lossLocal;
    __syncthreads();
    if (tid == 0) {
        atomicAdd(acc, (double)(wls[0] + wls[1] + wls[2] + wls[3]));
        __threadfence();
        unsigned int old = atomicAdd(cnt, 1u);
        if (old == (unsigned int)(gridDim.x - 1)) {
            __threadfence();
            unsigned long long bits = atomicAdd((unsigned long long*)acc, 0ULL);
            double v = __builtin_bit_cast(double, bits);
            out[0] = (float)(v * 1.25 / (double)((size_t)NN * DD));
        }
    }
}

extern "C" void kernel_launch(void* const* d_in, const int* in_sizes, int n_in,
                              void* d_out, int out_size, void* d_ws, size_t ws_size,
                              hipStream_t stream) {
    const float* x = (const float*)d_in[0];
    const float* cb = (const float*)d_in[1];
    float* out = (float*)d_out;

    double* acc = (double*)d_ws;                                   // 8 B
    unsigned int* cnt = (unsigned int*)((char*)d_ws + 8);          // 4 B
    unsigned int* sehl = (unsigned int*)((char*)d_ws + 4096);      // 4 KB
    unsigned short* cbh = (unsigned short*)((char*)d_ws + 8192);          // 128 KB
    unsigned short* cbl = (unsigned short*)((char*)d_ws + 8192 + 131072); // 128 KB

    hipMemsetAsync(d_ws, 0, 64, stream);

    vq_prep<<<16, 64, 0, stream>>>(cb, cbh, cbl, sehl);
    vq_main<<<NN / 128, 256, 0, stream>>>(x, cb, cbh, cbl, sehl, out, acc, cnt);
}